// Round 1
// baseline (851.507 us; speedup 1.0000x reference)
//
#include <hip/hip_runtime.h>
#include <cstdint>
#include <cstddef>

#define T_TOK 2048
#define H_DIM 1024
#define I_DIM 2816
#define E_NUM 8

typedef __attribute__((ext_vector_type(8))) short bf16x8;
typedef __attribute__((ext_vector_type(4))) float f32x4;

__device__ __forceinline__ uint16_t f2bf(float f) {
  union { float f; uint32_t u; } v; v.f = f;
  uint32_t r = v.u + 0x7FFF + ((v.u >> 16) & 1);
  return (uint16_t)(r >> 16);
}
__device__ __forceinline__ float bf2f(uint16_t h) {
  union { uint32_t u; float f; } v; v.u = ((uint32_t)h) << 16;
  return v.f;
}

// ---------------------------------------------------------------- convert x
__global__ void convert_x_kernel(const float* __restrict__ x,
                                 uint16_t* __restrict__ x16) {
  size_t i = ((size_t)blockIdx.x * 256 + threadIdx.x) * 8;
  float4 a = *(const float4*)(x + i);
  float4 b = *(const float4*)(x + i + 4);
  uint4 o;
  o.x = (uint32_t)f2bf(a.x) | ((uint32_t)f2bf(a.y) << 16);
  o.y = (uint32_t)f2bf(a.z) | ((uint32_t)f2bf(a.w) << 16);
  o.z = (uint32_t)f2bf(b.x) | ((uint32_t)f2bf(b.y) << 16);
  o.w = (uint32_t)f2bf(b.z) | ((uint32_t)f2bf(b.w) << 16);
  *(uint4*)(x16 + i) = o;
}

// ---------------------------------------------------------------- router
__global__ void router_kernel(const float* __restrict__ x,
                              const float* __restrict__ gw,
                              float* __restrict__ logits_out,
                              int* __restrict__ counts,
                              int* __restrict__ tok_list,
                              int* __restrict__ meta_e,
                              float* __restrict__ meta_w) {
  int t = blockIdx.x * 4 + (threadIdx.x >> 6);
  int lane = threadIdx.x & 63;
  const float* xr = x + (size_t)t * H_DIM;
  float xv[16];
#pragma unroll
  for (int i = 0; i < 16; ++i) xv[i] = xr[lane + i * 64];
  float lg[E_NUM];
#pragma unroll
  for (int e = 0; e < E_NUM; ++e) {
    const float* g = gw + e * H_DIM;
    float s = 0.f;
#pragma unroll
    for (int i = 0; i < 16; ++i) s += xv[i] * g[lane + i * 64];
#pragma unroll
    for (int off = 32; off > 0; off >>= 1) s += __shfl_down(s, off, 64);
    lg[e] = s;  // valid on lane 0
  }
  if (lane == 0) {
#pragma unroll
    for (int e = 0; e < E_NUM; ++e) logits_out[t * E_NUM + e] = lg[e];
    int e0 = 0; float l0 = lg[0];
    for (int e = 1; e < E_NUM; ++e) if (lg[e] > l0) { l0 = lg[e]; e0 = e; }
    int e1 = -1; float l1 = -1e30f;
    for (int e = 0; e < E_NUM; ++e)
      if (e != e0 && lg[e] > l1) { l1 = lg[e]; e1 = e; }
    float p1 = __expf(l1 - l0);
    float w0 = 1.f / (1.f + p1);
    float w1 = 1.f - w0;
    int s0 = atomicAdd(&counts[e0], 1);
    int s1 = atomicAdd(&counts[e1], 1);
    tok_list[e0 * T_TOK + s0] = t;
    tok_list[e1 * T_TOK + s1] = t;
    meta_e[2 * t]     = (e0 << 16) | s0;
    meta_e[2 * t + 1] = (e1 << 16) | s1;
    meta_w[2 * t]     = w0;
    meta_w[2 * t + 1] = w1;
  }
}

// ---------------------------------------------------------------- prefix sum
__global__ void prefix_kernel(const int* __restrict__ counts,
                              int* __restrict__ base) {
  if (threadIdx.x == 0 && blockIdx.x == 0) {
    int a = 0;
    for (int e = 0; e < E_NUM; ++e) { base[e] = a; a += counts[e]; }
  }
}

// ---------------------------------------------------------------- grouped GEMM
// C[rbase+slot, :] = A[slot, :] (bf16) @ W_e (fp32 -> bf16)    K x N weights
template <bool GATHER, bool OUT_BF16, int K, int N, int ASTRIDE>
__global__ __launch_bounds__(256, 2) void gemm_kernel(
    const uint16_t* __restrict__ Asrc, const float* __restrict__ W,
    void* __restrict__ Cdst, const int* __restrict__ counts,
    const int* __restrict__ base, const int* __restrict__ tok_list) {
  constexpr int BM = 128, BN = 128, BK = 32;
  constexpr int LDA = BK + 8;   // 40 bf16 -> 80 B rows, b128-aligned
  constexpr int LDB = BN + 2;   // 130 bf16 -> quads hit disjoint bank groups
  const int e  = blockIdx.x >> 4;
  const int mt = blockIdx.x & 15;
  const int nt = blockIdx.y;
  const int cnt = counts[e];
  if (mt * BM >= cnt) return;
  const int rbase = base[e];

  __shared__ uint16_t sA[BM * LDA];
  __shared__ uint16_t sB[BK * LDB];

  const int tid  = threadIdx.x;
  const int lane = tid & 63;
  const int wid  = tid >> 6;
  const int quad = lane >> 4;
  const int l16  = lane & 15;
  const int wm   = (wid >> 1) * 64;
  const int wn   = (wid & 1) * 64;

  // A staging: thread -> (row, 16-elem segment), source pointer hoisted
  const int arow = tid >> 1;
  const int aseg = tid & 1;
  {
  }
  int slot0 = mt * BM + arow;
  int s2 = slot0 < cnt ? slot0 : cnt - 1;
  const uint16_t* aptr;
  if (GATHER) {
    int tok = tok_list[e * T_TOK + s2];
    aptr = Asrc + (size_t)tok * ASTRIDE + aseg * 16;
  } else {
    aptr = Asrc + (size_t)(rbase + s2) * ASTRIDE + aseg * 16;
  }

  const float* wbase = W + (size_t)e * K * N + (size_t)nt * BN;
  const int bk = tid >> 5;        // 0..7
  const int bn = (tid & 31) * 4;  // 0..124

  f32x4 acc[4][4];
#pragma unroll
  for (int i = 0; i < 4; ++i)
#pragma unroll
    for (int j = 0; j < 4; ++j) {
      f32x4 z = {0.f, 0.f, 0.f, 0.f};
      acc[i][j] = z;
    }

  for (int k0 = 0; k0 < K; k0 += BK) {
    // stage A tile [BM][BK]
    uint4 av0 = *(const uint4*)(aptr + k0);
    uint4 av1 = *(const uint4*)(aptr + k0 + 8);
    *(uint4*)&sA[arow * LDA + aseg * 16]     = av0;
    *(uint4*)&sA[arow * LDA + aseg * 16 + 8] = av1;
    // stage B tile [BK][BN], fp32 -> bf16
#pragma unroll
    for (int i = 0; i < 4; ++i) {
      int k = bk + i * 8;
      const float4 f = *(const float4*)(wbase + (size_t)(k0 + k) * N + bn);
      uint32_t p0 = (uint32_t)f2bf(f.x) | ((uint32_t)f2bf(f.y) << 16);
      uint32_t p1 = (uint32_t)f2bf(f.z) | ((uint32_t)f2bf(f.w) << 16);
      uint32_t* dst = (uint32_t*)&sB[k * LDB + bn];
      dst[0] = p0;
      dst[1] = p1;
    }
    __syncthreads();

    bf16x8 af[4], bfr[4];
#pragma unroll
    for (int i = 0; i < 4; ++i)
      af[i] = *(const bf16x8*)&sA[(wm + i * 16 + l16) * LDA + quad * 8];
#pragma unroll
    for (int j = 0; j < 4; ++j) {
      bf16x8 b;
#pragma unroll
      for (int kk = 0; kk < 8; ++kk)
        b[kk] = (short)sB[(quad * 8 + kk) * LDB + wn + j * 16 + l16];
      bfr[j] = b;
    }
#pragma unroll
    for (int i = 0; i < 4; ++i)
#pragma unroll
      for (int j = 0; j < 4; ++j)
        acc[i][j] = __builtin_amdgcn_mfma_f32_16x16x32_bf16(af[i], bfr[j],
                                                            acc[i][j], 0, 0, 0);
    __syncthreads();
  }

  // epilogue: D row = quad*4 + reg, col = lane&15
#pragma unroll
  for (int i = 0; i < 4; ++i) {
#pragma unroll
    for (int r = 0; r < 4; ++r) {
      int mrow = wm + i * 16 + quad * 4 + r;
      int sl = mt * BM + mrow;
      if (sl < cnt) {
        size_t rowoff = (size_t)(rbase + sl) * N + (size_t)nt * BN;
#pragma unroll
        for (int j = 0; j < 4; ++j) {
          int col = wn + j * 16 + l16;
          float v = acc[i][j][r];
          if (OUT_BF16)
            ((uint16_t*)Cdst)[rowoff + col] = f2bf(v);
          else
            ((float*)Cdst)[rowoff + col] = v;
        }
      }
    }
  }
}

// ---------------------------------------------------------------- h = silu(g)*u
__global__ void silu_mul_kernel(uint16_t* __restrict__ g,
                                const uint16_t* __restrict__ u) {
  size_t i = ((size_t)blockIdx.x * 256 + threadIdx.x) * 8;
  uint4 gv = *(const uint4*)(g + i);
  uint4 uv = *(const uint4*)(u + i);
  uint32_t* gp = (uint32_t*)&gv;
  uint32_t* up = (uint32_t*)&uv;
  uint4 out;
  uint32_t* op = (uint32_t*)&out;
#pragma unroll
  for (int k = 0; k < 4; ++k) {
    float g0 = bf2f((uint16_t)(gp[k] & 0xFFFF));
    float g1 = bf2f((uint16_t)(gp[k] >> 16));
    float u0 = bf2f((uint16_t)(up[k] & 0xFFFF));
    float u1 = bf2f((uint16_t)(up[k] >> 16));
    float h0 = g0 / (1.f + __expf(-g0)) * u0;
    float h1 = g1 / (1.f + __expf(-g1)) * u1;
    op[k] = (uint32_t)f2bf(h0) | ((uint32_t)f2bf(h1) << 16);
  }
  *(uint4*)(g + i) = out;
}

// ---------------------------------------------------------------- combine
__global__ void combine_kernel(const float* __restrict__ y,
                               const int* __restrict__ base,
                               const int* __restrict__ meta_e,
                               const float* __restrict__ meta_w,
                               float* __restrict__ out) {
  int t = blockIdx.x;
  int me0 = meta_e[2 * t], me1 = meta_e[2 * t + 1];
  float w0 = meta_w[2 * t], w1 = meta_w[2 * t + 1];
  size_t r0 = (size_t)(base[me0 >> 16] + (me0 & 0xFFFF));
  size_t r1 = (size_t)(base[me1 >> 16] + (me1 & 0xFFFF));
  int c = threadIdx.x * 4;
  float4 a = *(const float4*)&y[r0 * H_DIM + c];
  float4 b = *(const float4*)&y[r1 * H_DIM + c];
  float4 o;
  o.x = w0 * a.x + w1 * b.x;
  o.y = w0 * a.y + w1 * b.y;
  o.z = w0 * a.z + w1 * b.z;
  o.w = w0 * a.w + w1 * b.w;
  *(float4*)&out[(size_t)t * H_DIM + c] = o;
}

// ---------------------------------------------------------------- launch
extern "C" void kernel_launch(void* const* d_in, const int* in_sizes, int n_in,
                              void* d_out, int out_size, void* d_ws,
                              size_t ws_size, hipStream_t stream) {
  const float* x      = (const float*)d_in[0];
  const float* gate_w = (const float*)d_in[1];
  const float* w_gate = (const float*)d_in[2];
  const float* w_up   = (const float*)d_in[3];
  const float* w_down = (const float*)d_in[4];
  float* out = (float*)d_out;
  float* logits_out = out + (size_t)T_TOK * H_DIM;

  char* ws = (char*)d_ws;
  int*      counts   = (int*)(ws + 0);                       // 32 B
  int*      base     = (int*)(ws + 256);                     // 32 B
  int*      meta_e   = (int*)(ws + 512);                     // 16 KB
  float*    meta_w   = (float*)(ws + 512 + 16384);           // 16 KB
  int*      tok_list = (int*)(ws + 33280);                   // 64 KB
  uint16_t* x16      = (uint16_t*)(ws + 98816);              // 4 MB
  uint16_t* gbuf     = (uint16_t*)(ws + 4293120);            // 23.07 MB
  uint16_t* ubuf     = (uint16_t*)(ws + 27361792);           // 23.07 MB
  float*    ybuf     = (float*)(ws + 50430464);              // 16.78 MB
  // total ws use: 67,207,680 bytes

  hipMemsetAsync(counts, 0, E_NUM * sizeof(int), stream);
  convert_x_kernel<<<1024, 256, 0, stream>>>(x, x16);
  router_kernel<<<512, 256, 0, stream>>>(x, gate_w, logits_out, counts,
                                         tok_list, meta_e, meta_w);
  prefix_kernel<<<1, 64, 0, stream>>>(counts, base);
  gemm_kernel<true, true, H_DIM, I_DIM, H_DIM>
      <<<dim3(E_NUM * 16, I_DIM / 128), 256, 0, stream>>>(
          x16, w_gate, gbuf, counts, base, tok_list);
  gemm_kernel<true, true, H_DIM, I_DIM, H_DIM>
      <<<dim3(E_NUM * 16, I_DIM / 128), 256, 0, stream>>>(
          x16, w_up, ubuf, counts, base, tok_list);
  silu_mul_kernel<<<5632, 256, 0, stream>>>(gbuf, ubuf);
  gemm_kernel<false, false, I_DIM, H_DIM, I_DIM>
      <<<dim3(E_NUM * 16, H_DIM / 128), 256, 0, stream>>>(
          gbuf, w_down, ybuf, counts, base, tok_list);
  combine_kernel<<<T_TOK, 256, 0, stream>>>(ybuf, base, meta_e, meta_w, out);
}

// Round 2
// 707.214 us; speedup vs baseline: 1.2040x; 1.2040x over previous
//
#include <hip/hip_runtime.h>
#include <cstdint>
#include <cstddef>

#define T_TOK 2048
#define H_DIM 1024
#define I_DIM 2816
#define E_NUM 8

typedef __attribute__((ext_vector_type(8))) short bf16x8;
typedef __attribute__((ext_vector_type(4))) float f32x4;

__device__ __forceinline__ uint16_t f2bf(float f) {
  union { float f; uint32_t u; } v; v.f = f;
  uint32_t r = v.u + 0x7FFF + ((v.u >> 16) & 1);
  return (uint16_t)(r >> 16);
}
__device__ __forceinline__ float bf2f(uint16_t h) {
  union { uint32_t u; float f; } v; v.u = ((uint32_t)h) << 16;
  return v.f;
}

// async global -> LDS, 16 B per lane; LDS dest must be wave-uniform base
__device__ __forceinline__ void gld16(const uint16_t* g, uint16_t* l) {
  __builtin_amdgcn_global_load_lds(
      (const __attribute__((address_space(1))) uint32_t*)g,
      (__attribute__((address_space(3))) uint32_t*)l, 16, 0, 0);
}

// ---------------------------------------------------------------- convert x
__global__ void convert_x_kernel(const float* __restrict__ x,
                                 uint16_t* __restrict__ x16) {
  size_t i = ((size_t)blockIdx.x * 256 + threadIdx.x) * 8;
  float4 a = *(const float4*)(x + i);
  float4 b = *(const float4*)(x + i + 4);
  uint4 o;
  o.x = (uint32_t)f2bf(a.x) | ((uint32_t)f2bf(a.y) << 16);
  o.y = (uint32_t)f2bf(a.z) | ((uint32_t)f2bf(a.w) << 16);
  o.z = (uint32_t)f2bf(b.x) | ((uint32_t)f2bf(b.y) << 16);
  o.w = (uint32_t)f2bf(b.z) | ((uint32_t)f2bf(b.w) << 16);
  *(uint4*)(x16 + i) = o;
}

// ------------------------------------------------- weight fp32[K][N] -> bf16[N][K]
__global__ void transpose_conv_kernel(const float* __restrict__ W,
                                      uint16_t* __restrict__ WT,
                                      int K, int N) {
  __shared__ uint16_t tile[64][72];
  const int e = blockIdx.z;
  const int k0 = blockIdx.x * 64;
  const int n0 = blockIdx.y * 64;
  const float* src = W + ((size_t)e * K + k0) * N + n0;
  uint16_t* dst = WT + ((size_t)e * N + n0) * K + k0;
  const int t = threadIdx.x;
#pragma unroll
  for (int i = 0; i < 4; ++i) {
    int idx = t + 256 * i;        // 0..1023
    int r = idx >> 4;             // 0..63
    int c4 = (idx & 15) << 2;     // 0..60
    float4 f = *(const float4*)(src + (size_t)r * N + c4);
    tile[r][c4 + 0] = f2bf(f.x);
    tile[r][c4 + 1] = f2bf(f.y);
    tile[r][c4 + 2] = f2bf(f.z);
    tile[r][c4 + 3] = f2bf(f.w);
  }
  __syncthreads();
  const int n = t >> 2;           // 0..63
  const int ks = (t & 3) << 4;    // 0,16,32,48
  uint16_t vals[16];
#pragma unroll
  for (int j = 0; j < 16; ++j) vals[j] = tile[ks + j][n];
  *(uint4*)(dst + (size_t)n * K + ks) = *(uint4*)&vals[0];
  *(uint4*)(dst + (size_t)n * K + ks + 8) = *(uint4*)&vals[8];
}

// ---------------------------------------------------------------- router
__global__ void router_kernel(const float* __restrict__ x,
                              const float* __restrict__ gw,
                              float* __restrict__ logits_out,
                              int* __restrict__ counts,
                              int* __restrict__ tok_list,
                              int* __restrict__ meta_e,
                              float* __restrict__ meta_w) {
  int t = blockIdx.x * 4 + (threadIdx.x >> 6);
  int lane = threadIdx.x & 63;
  const float* xr = x + (size_t)t * H_DIM;
  float xv[16];
#pragma unroll
  for (int i = 0; i < 16; ++i) xv[i] = xr[lane + i * 64];
  float lg[E_NUM];
#pragma unroll
  for (int e = 0; e < E_NUM; ++e) {
    const float* g = gw + e * H_DIM;
    float s = 0.f;
#pragma unroll
    for (int i = 0; i < 16; ++i) s += xv[i] * g[lane + i * 64];
#pragma unroll
    for (int off = 32; off > 0; off >>= 1) s += __shfl_down(s, off, 64);
    lg[e] = s;
  }
  if (lane == 0) {
#pragma unroll
    for (int e = 0; e < E_NUM; ++e) logits_out[t * E_NUM + e] = lg[e];
    int e0 = 0; float l0 = lg[0];
    for (int e = 1; e < E_NUM; ++e) if (lg[e] > l0) { l0 = lg[e]; e0 = e; }
    int e1 = -1; float l1 = -1e30f;
    for (int e = 0; e < E_NUM; ++e)
      if (e != e0 && lg[e] > l1) { l1 = lg[e]; e1 = e; }
    float p1 = __expf(l1 - l0);
    float w0 = 1.f / (1.f + p1);
    float w1 = 1.f - w0;
    int s0 = atomicAdd(&counts[e0], 1);
    int s1 = atomicAdd(&counts[e1], 1);
    tok_list[e0 * T_TOK + s0] = t;
    tok_list[e1 * T_TOK + s1] = t;
    meta_e[2 * t]     = (e0 << 16) | s0;
    meta_e[2 * t + 1] = (e1 << 16) | s1;
    meta_w[2 * t]     = w0;
    meta_w[2 * t + 1] = w1;
  }
}

// ---------------------------------------------------------------- prefix sum
__global__ void prefix_kernel(const int* __restrict__ counts,
                              int* __restrict__ base) {
  if (threadIdx.x == 0 && blockIdx.x == 0) {
    int a = 0;
    for (int e = 0; e < E_NUM; ++e) { base[e] = a; a += counts[e]; }
  }
}

// ------------------------------------------------- fused gate+up GEMM + silu*mul
// A: gathered token rows (bf16 [T][H]);  B: wgT/wuT bf16 [E][I][H]
// out: hbuf bf16 [4096][I],  h = silu(g) * u
__global__ __launch_bounds__(256, 2) void gemm_gu_kernel(
    const uint16_t* __restrict__ x16, const uint16_t* __restrict__ wgT,
    const uint16_t* __restrict__ wuT, uint16_t* __restrict__ hbuf,
    const int* __restrict__ counts, const int* __restrict__ base,
    const int* __restrict__ tok_list) {
  constexpr int K = H_DIM, NI = I_DIM, BM = 128, BN = 128, BK = 32;
  const int e  = blockIdx.x >> 4;
  const int mt = blockIdx.x & 15;
  const int nt = blockIdx.y;
  const int cnt = counts[e];
  if (mt * BM >= cnt) return;
  const int rbase = base[e];

  __shared__ uint16_t sA[BM * BK];
  __shared__ uint16_t sBg[BN * BK];
  __shared__ uint16_t sBu[BN * BK];

  const int tid  = threadIdx.x;
  const int lane = tid & 63;
  const int wid  = tid >> 6;
  const int quad = lane >> 4;
  const int l16  = lane & 15;
  const int wm   = (wid >> 1) * 64;
  const int wn   = (wid & 1) * 64;

  // staging: issue r covers block-rows r*64 + wid*16 .. +15; lane -> row,seg
  const int seg  = lane & 3;
  const int row0 = wid * 16 + (lane >> 2);
  const uint16_t* aptr[2];
  const uint16_t* bgptr[2];
  const uint16_t* buptr[2];
#pragma unroll
  for (int r = 0; r < 2; ++r) {
    int slot = mt * BM + row0 + r * 64;
    int s2 = slot < cnt ? slot : cnt - 1;
    int tok = tok_list[e * T_TOK + s2];
    aptr[r] = x16 + (size_t)tok * K + seg * 8;
    int n = nt * BN + row0 + r * 64;
    bgptr[r] = wgT + ((size_t)e * NI + n) * K + seg * 8;
    buptr[r] = wuT + ((size_t)e * NI + n) * K + seg * 8;
  }

  f32x4 accg[4][4], accu[4][4];
#pragma unroll
  for (int i = 0; i < 4; ++i)
#pragma unroll
    for (int j = 0; j < 4; ++j) {
      f32x4 z = {0.f, 0.f, 0.f, 0.f};
      accg[i][j] = z; accu[i][j] = z;
    }

  for (int k0 = 0; k0 < K; k0 += BK) {
#pragma unroll
    for (int r = 0; r < 2; ++r) {
      uint16_t* ldst = (uint16_t*)0 + r * 2048 + wid * 512;  // elem offset
      gld16(aptr[r] + k0,  &sA[r * 2048 + wid * 512]);
      gld16(bgptr[r] + k0, &sBg[r * 2048 + wid * 512]);
      gld16(buptr[r] + k0, &sBu[r * 2048 + wid * 512]);
      (void)ldst;
    }
    __syncthreads();
    bf16x8 af[4], bg[4], bu[4];
#pragma unroll
    for (int i = 0; i < 4; ++i)
      af[i] = *(const bf16x8*)&sA[(wm + i * 16 + l16) * BK + quad * 8];
#pragma unroll
    for (int j = 0; j < 4; ++j) {
      bg[j] = *(const bf16x8*)&sBg[(wn + j * 16 + l16) * BK + quad * 8];
      bu[j] = *(const bf16x8*)&sBu[(wn + j * 16 + l16) * BK + quad * 8];
    }
#pragma unroll
    for (int i = 0; i < 4; ++i)
#pragma unroll
      for (int j = 0; j < 4; ++j) {
        accg[i][j] = __builtin_amdgcn_mfma_f32_16x16x32_bf16(af[i], bg[j],
                                                             accg[i][j], 0, 0, 0);
        accu[i][j] = __builtin_amdgcn_mfma_f32_16x16x32_bf16(af[i], bu[j],
                                                             accu[i][j], 0, 0, 0);
      }
    __syncthreads();
  }

  // epilogue: h = silu(g) * u, D row = quad*4+reg, col = lane&15
#pragma unroll
  for (int i = 0; i < 4; ++i) {
#pragma unroll
    for (int r = 0; r < 4; ++r) {
      int sl = mt * BM + wm + i * 16 + quad * 4 + r;
      if (sl < cnt) {
        size_t rowoff = (size_t)(rbase + sl) * NI + (size_t)nt * BN;
#pragma unroll
        for (int j = 0; j < 4; ++j) {
          float g = accg[i][j][r];
          float u = accu[i][j][r];
          float h = g / (1.f + __expf(-g)) * u;
          hbuf[rowoff + wn + j * 16 + l16] = f2bf(h);
        }
      }
    }
  }
}

// ------------------------------------------------- down GEMM (m97 shape)
// A: hbuf bf16 [4096][I] (rows already grouped);  B: wdT bf16 [E][H][I]
// out: ybuf fp32 [4096][H]
__global__ __launch_bounds__(256, 2) void gemm_down_kernel(
    const uint16_t* __restrict__ hbuf, const uint16_t* __restrict__ wdT,
    float* __restrict__ ybuf, const int* __restrict__ counts,
    const int* __restrict__ base) {
  constexpr int K = I_DIM, N = H_DIM, BM = 128, BN = 128, BK = 32;
  const int e  = blockIdx.x >> 4;
  const int mt = blockIdx.x & 15;
  const int nt = blockIdx.y;
  const int cnt = counts[e];
  if (mt * BM >= cnt) return;
  const int rbase = base[e];

  __shared__ uint16_t sA[BM * BK];
  __shared__ uint16_t sB[BN * BK];

  const int tid  = threadIdx.x;
  const int lane = tid & 63;
  const int wid  = tid >> 6;
  const int quad = lane >> 4;
  const int l16  = lane & 15;
  const int wm   = (wid >> 1) * 64;
  const int wn   = (wid & 1) * 64;

  const int seg  = lane & 3;
  const int row0 = wid * 16 + (lane >> 2);
  const uint16_t* aptr[2];
  const uint16_t* bptr[2];
#pragma unroll
  for (int r = 0; r < 2; ++r) {
    int slot = mt * BM + row0 + r * 64;
    int s2 = slot < cnt ? slot : cnt - 1;
    aptr[r] = hbuf + (size_t)(rbase + s2) * K + seg * 8;
    int n = nt * BN + row0 + r * 64;
    bptr[r] = wdT + ((size_t)e * N + n) * K + seg * 8;
  }

  f32x4 acc[4][4];
#pragma unroll
  for (int i = 0; i < 4; ++i)
#pragma unroll
    for (int j = 0; j < 4; ++j) {
      f32x4 z = {0.f, 0.f, 0.f, 0.f};
      acc[i][j] = z;
    }

  for (int k0 = 0; k0 < K; k0 += BK) {
#pragma unroll
    for (int r = 0; r < 2; ++r) {
      gld16(aptr[r] + k0, &sA[r * 2048 + wid * 512]);
      gld16(bptr[r] + k0, &sB[r * 2048 + wid * 512]);
    }
    __syncthreads();
    bf16x8 af[4], bf[4];
#pragma unroll
    for (int i = 0; i < 4; ++i)
      af[i] = *(const bf16x8*)&sA[(wm + i * 16 + l16) * BK + quad * 8];
#pragma unroll
    for (int j = 0; j < 4; ++j)
      bf[j] = *(const bf16x8*)&sB[(wn + j * 16 + l16) * BK + quad * 8];
#pragma unroll
    for (int i = 0; i < 4; ++i)
#pragma unroll
      for (int j = 0; j < 4; ++j)
        acc[i][j] = __builtin_amdgcn_mfma_f32_16x16x32_bf16(af[i], bf[j],
                                                            acc[i][j], 0, 0, 0);
    __syncthreads();
  }

#pragma unroll
  for (int i = 0; i < 4; ++i) {
#pragma unroll
    for (int r = 0; r < 4; ++r) {
      int sl = mt * BM + wm + i * 16 + quad * 4 + r;
      if (sl < cnt) {
        size_t rowoff = (size_t)(rbase + sl) * N + (size_t)nt * BN;
#pragma unroll
        for (int j = 0; j < 4; ++j)
          ybuf[rowoff + wn + j * 16 + l16] = acc[i][j][r];
      }
    }
  }
}

// ---------------------------------------------------------------- combine
__global__ void combine_kernel(const float* __restrict__ y,
                               const int* __restrict__ base,
                               const int* __restrict__ meta_e,
                               const float* __restrict__ meta_w,
                               float* __restrict__ out) {
  int t = blockIdx.x;
  int me0 = meta_e[2 * t], me1 = meta_e[2 * t + 1];
  float w0 = meta_w[2 * t], w1 = meta_w[2 * t + 1];
  size_t r0 = (size_t)(base[me0 >> 16] + (me0 & 0xFFFF));
  size_t r1 = (size_t)(base[me1 >> 16] + (me1 & 0xFFFF));
  int c = threadIdx.x * 4;
  float4 a = *(const float4*)&y[r0 * H_DIM + c];
  float4 b = *(const float4*)&y[r1 * H_DIM + c];
  float4 o;
  o.x = w0 * a.x + w1 * b.x;
  o.y = w0 * a.y + w1 * b.y;
  o.z = w0 * a.z + w1 * b.z;
  o.w = w0 * a.w + w1 * b.w;
  *(float4*)&out[(size_t)t * H_DIM + c] = o;
}

// ---------------------------------------------------------------- launch
extern "C" void kernel_launch(void* const* d_in, const int* in_sizes, int n_in,
                              void* d_out, int out_size, void* d_ws,
                              size_t ws_size, hipStream_t stream) {
  const float* x      = (const float*)d_in[0];
  const float* gate_w = (const float*)d_in[1];
  const float* w_gate = (const float*)d_in[2];
  const float* w_up   = (const float*)d_in[3];
  const float* w_down = (const float*)d_in[4];
  float* out = (float*)d_out;
  float* logits_out = out + (size_t)T_TOK * H_DIM;

  char* ws = (char*)d_ws;
  int*      counts   = (int*)(ws + 0);
  int*      base     = (int*)(ws + 256);
  int*      meta_e   = (int*)(ws + 512);
  float*    meta_w   = (float*)(ws + 16896);
  int*      tok_list = (int*)(ws + 33280);
  uint16_t* x16      = (uint16_t*)(ws + 98816);            // 4 MB
  uint16_t* wgT      = (uint16_t*)(ws + 4293120);          // 46.1 MB
  uint16_t* wuT      = (uint16_t*)(ws + 50430464);         // 46.1 MB
  uint16_t* wdT      = (uint16_t*)(ws + 96567808);         // 46.1 MB
  uint16_t* hbuf     = (uint16_t*)(ws + 142705152);        // 23.1 MB
  float*    ybuf     = (float*)(ws + 165773824);           // 16.8 MB
  // total ws use: 182,551,040 bytes

  hipMemsetAsync(counts, 0, E_NUM * sizeof(int), stream);
  convert_x_kernel<<<1024, 256, 0, stream>>>(x, x16);
  router_kernel<<<512, 256, 0, stream>>>(x, gate_w, logits_out, counts,
                                         tok_list, meta_e, meta_w);
  prefix_kernel<<<1, 64, 0, stream>>>(counts, base);
  transpose_conv_kernel<<<dim3(H_DIM / 64, I_DIM / 64, E_NUM), 256, 0, stream>>>(
      w_gate, wgT, H_DIM, I_DIM);
  transpose_conv_kernel<<<dim3(H_DIM / 64, I_DIM / 64, E_NUM), 256, 0, stream>>>(
      w_up, wuT, H_DIM, I_DIM);
  transpose_conv_kernel<<<dim3(I_DIM / 64, H_DIM / 64, E_NUM), 256, 0, stream>>>(
      w_down, wdT, I_DIM, H_DIM);
  gemm_gu_kernel<<<dim3(E_NUM * 16, I_DIM / 128), 256, 0, stream>>>(
      x16, wgT, wuT, hbuf, counts, base, tok_list);
  gemm_down_kernel<<<dim3(E_NUM * 16, H_DIM / 128), 256, 0, stream>>>(
      hbuf, wdT, ybuf, counts, base);
  combine_kernel<<<T_TOK, 256, 0, stream>>>(ybuf, base, meta_e, meta_w, out);
}